// Round 5
// baseline (756.228 us; speedup 1.0000x reference)
//
#include <hip/hip_runtime.h>

// GRU scan: B=2048, T=2048, D=3, H=32. out[b,t] = h_new[b,t][0].
// Round-5: r4 structure (1 batch elem / 64-lane wave, unit x K-half split,
// sigma-split, x direct from global, single h write, no s_barrier) with the
// NaN fixed: inline-asm permlane (register-aliasing hazard when both "+v"
// operands hold the same value -> same-physreg swap -> undefined bits) is
// replaced by the compiler-modeled __builtin_amdgcn_permlane32_swap, which
// returns BOTH outputs. ds_bpermute fallback if the builtin is unavailable.
// DS ops/step: 12 (r3) -> 5 (4x ds_read_b128 + 1 ds_write_b32).

#define GRU_B 2048
#define GRU_T 2048
#define GRU_D 3
#define GRU_H 32
#define CHUNK 16  // output-capture granularity

// s_waitcnt imm: lgkmcnt(0), vmcnt=63 (no wait), expcnt=7 (no wait)
#define WAIT_LGKM0 0xC07F

__device__ __forceinline__ float fast_sigmoid(float x) {
    float e = __expf(-x);                       // v_mul(log2e)+v_exp
    return __builtin_amdgcn_rcpf(1.0f + e);     // e=inf -> 0 (correct limit)
}
__device__ __forceinline__ float fast_tanh(float x) {
    float e = __expf(2.0f * x);                 // overflow -> inf -> tanh=1
    return 1.0f - 2.0f * __builtin_amdgcn_rcpf(e + 1.0f);
}

#if __has_builtin(__builtin_amdgcn_permlane32_swap)
#define HAVE_PLSWAP 1
typedef int v2i __attribute__((ext_vector_type(2)));
// Half-broadcasts of v: lo_b = [v_lo, v_lo], hi_b = [v_hi, v_hi].
// (permlane32_swap(v, v): new_vdst = [v.lo, v.lo], new_vsrc = [v.hi, v.hi])
__device__ __forceinline__ void bcast_halves(float v, float& lo_b, float& hi_b) {
    v2i r = __builtin_amdgcn_permlane32_swap(__float_as_int(v), __float_as_int(v),
                                             false, false);
    lo_b = __int_as_float(r.x);
    hi_b = __int_as_float(r.y);
}
#else
#define HAVE_PLSWAP 0
__device__ __forceinline__ float xor32(float v) {
    int paddr = (int)((threadIdx.x ^ 32u) << 2);
    return __int_as_float(__builtin_amdgcn_ds_bpermute(paddr, __float_as_int(v)));
}
#endif

__global__ __launch_bounds__(64, 2) void gru_scan_kernel(
    const float* __restrict__ inp,     // [B, T, D]
    const float* __restrict__ w_ih,    // [3H, D]
    const float* __restrict__ w_hh,    // [3H, H]
    const float* __restrict__ bias,    // [3H]
    const float* __restrict__ bias_n,  // [H]
    float* __restrict__ out)           // [B, T]
{
    // h2 (floats): [0..31] the h copy, [64..95] half1 dump rows.
    __shared__ __align__(16) float h2[96];

    const int lane  = threadIdx.x;       // 0..63
    const int unit  = lane & 31;         // hidden unit owned
    const int half  = lane >> 5;         // K-half: 0 -> k 0..15, 1 -> k 16..31
    const int b     = blockIdx.x;
    const bool lo32 = (lane < 32);

    // Gate rows (sigma-split): rowA = my sigmoid gate (r for half0, z for
    // half1); rowB = other sigmoid gate (partial computed to exchange);
    // rowC = n gate. All over my K-half columns.
    const int rowA = unit + 32 * half;
    const int rowB = unit + 32 * (1 - half);
    const int rowC = 2 * GRU_H + unit;
    const int kofs = 16 * half;

    float wa[16], wb[16], wc[16];
    {
        const float4* pa = (const float4*)(w_hh + (size_t)rowA * GRU_H + kofs);
        const float4* pb = (const float4*)(w_hh + (size_t)rowB * GRU_H + kofs);
        const float4* pc = (const float4*)(w_hh + (size_t)rowC * GRU_H + kofs);
#pragma unroll
        for (int q = 0; q < 4; ++q) {
            float4 A = pa[q], Bv = pb[q], Cv = pc[q];
            wa[4*q+0]=A.x;  wa[4*q+1]=A.y;  wa[4*q+2]=A.z;  wa[4*q+3]=A.w;
            wb[4*q+0]=Bv.x; wb[4*q+1]=Bv.y; wb[4*q+2]=Bv.z; wb[4*q+3]=Bv.w;
            wc[4*q+0]=Cv.x; wc[4*q+1]=Cv.y; wc[4*q+2]=Cv.z; wc[4*q+3]=Cv.w;
        }
    }
    float wia[GRU_D], wic[GRU_D];
#pragma unroll
    for (int d = 0; d < GRU_D; ++d) {
        wia[d] = w_ih[(size_t)rowA * GRU_D + d];
        wic[d] = w_ih[(size_t)rowC * GRU_D + d];
    }
    const float bA = bias[rowA];
    const float bC = bias[rowC] + bias_n[unit];

    const float* xb = inp + (size_t)b * GRU_T * GRU_D;
    float*       ob = out + (size_t)b * GRU_T;

    float h = 0.0f;       // own unit's h (true trajectory in half0; bounded in half1)
    float outreg = 0.0f;  // chunk-local captured output (lane t <- step t)

    h2[lane < 32 ? lane : 32 + lane] = 0.0f;  // zero the copy (+ dump, harmless)
    __builtin_amdgcn_s_waitcnt(WAIT_LGKM0);

    // gather: half0 reads floats 0..15, half1 reads 16..31 (2 broadcast addrs)
    const float4* hv = (const float4*)(h2 + kofs);
    // write: half0 -> h2[unit]; half1 -> h2[64+unit] (dump)
    const int wbase = unit + 64 * half;

    for (int c = 0; c < GRU_T / CHUNK; ++c) {
        const float* xs = xb + c * (CHUNK * GRU_D);  // wave-uniform base

#pragma unroll
        for (int s = 0; s < CHUNK; ++s) {
            // h all-gather: 4 x ds_read_b128, broadcast
            float hk[16];
#pragma unroll
            for (int q = 0; q < 4; ++q) {
                float4 v = hv[q];
                hk[4*q+0]=v.x; hk[4*q+1]=v.y; hk[4*q+2]=v.z; hk[4*q+3]=v.w;
            }
            // x: wave-uniform global reads (scalar pipe; off the LDS pipe)
            const float x0 = xs[3 * s + 0];
            const float x1 = xs[3 * s + 1];
            const float x2 = xs[3 * s + 2];

            // input projections (+bias): my sigmoid gate + n gate
            const float aM = fmaf(wia[2], x2, fmaf(wia[1], x1, fmaf(wia[0], x0, bA)));
            const float aN = fmaf(wic[2], x2, fmaf(wic[1], x1, fmaf(wic[0], x0, bC)));

            // K-half partials
            float A = 0.0f, Bp = 0.0f, Cp = 0.0f;
#pragma unroll
            for (int k = 0; k < 16; ++k) {
                A  = fmaf(wa[k], hk[k], A);
                Bp = fmaf(wb[k], hk[k], Bp);
                Cp = fmaf(wc[k], hk[k], Cp);
            }

#if HAVE_PLSWAP
            // n-gate: P0 + P1 in all lanes, select-free
            float cLo, cHi;
            bcast_halves(Cp, cLo, cHi);
            const float gN = cLo + cHi;
            // my sigmoid gate: add the OTHER half's partial of MY gate
            float bLo, bHi;
            bcast_halves(Bp, bLo, bHi);           // bLo=[Bz0,Bz0], bHi=[Br1,Br1]
            const float gM = aM + A + (lo32 ? bHi : bLo);
            const float sg = fast_sigmoid(gM);    // half0: r, half1: z
            // z to all lanes: hi-broadcast of sg
            float sLo, sHi;
            bcast_halves(sg, sLo, sHi);
            const float zg = sHi;                 // [z, z]
#else
            const float gN = Cp + xor32(Cp);
            const float gM = aM + A + xor32(Bp);
            const float sg = fast_sigmoid(gM);
            const float zg = lo32 ? xor32(sg) : sg;
#endif

            const float n    = fast_tanh(fmaf(sg, gN, aN));  // valid in half0
            const float hnew = fmaf(zg, h - n, n);           // (1-z)*n + z*h

            // hk[0] in half0 = h[0] BEFORE this step = output of step s-1
            if (lane == s - 1) outreg = hk[0];

            h = hnew;
            h2[wbase] = h;                               // 1 ds_write
            __builtin_amdgcn_s_waitcnt(WAIT_LGKM0);      // visible before next gather
        }

        // last chunk-step's output: h[0] after step CHUNK-1
        {
            const float h0 = h2[0];
            if (lane == CHUNK - 1) outreg = h0;
        }
        if (lane < CHUNK) ob[c * CHUNK + lane] = outreg;  // coalesced store
    }
}

extern "C" void kernel_launch(void* const* d_in, const int* in_sizes, int n_in,
                              void* d_out, int out_size, void* d_ws, size_t ws_size,
                              hipStream_t stream) {
    const float* inp    = (const float*)d_in[0];
    const float* w_ih   = (const float*)d_in[1];
    const float* w_hh   = (const float*)d_in[2];
    const float* bias   = (const float*)d_in[3];
    const float* bias_n = (const float*)d_in[4];
    float* out = (float*)d_out;

    dim3 grid(GRU_B);
    dim3 block(64);
    gru_scan_kernel<<<grid, block, 0, stream>>>(inp, w_ih, w_hh, bias, bias_n, out);
}